// Round 3
// baseline (1143.637 us; speedup 1.0000x reference)
//
#include <hip/hip_runtime.h>
#include <math.h>

#define NB    4
#define NPTS  2048
#define ROWS  (NB*NPTS)   // 8192
#define CIN   64
#define COUT  256
#define KNBR  21
#define NHEADS 7
#define WCH   64
#define DSH   32

// ---------------------------------------------------------------- transpose f [B,64,2048] -> ft [B*2048,64]
__global__ __launch_bounds__(256) void transpose_f(const float* __restrict__ f, float* __restrict__ ft) {
    __shared__ float tile[64][65];
    int b  = blockIdx.x >> 5;
    int nt = blockIdx.x & 31;
    int t  = threadIdx.x;
    for (int e = t; e < 4096; e += 256) {
        int cc = e >> 6, nn = e & 63;
        tile[cc][nn] = f[(size_t)b*CIN*NPTS + (size_t)cc*NPTS + nt*64 + nn];
    }
    __syncthreads();
    for (int e = t; e < 4096; e += 256) {
        int nn = e >> 6, cc = e & 63;
        ft[((size_t)(b*NPTS + nt*64 + nn))*64 + cc] = tile[cc][nn];
    }
}

// ---------------------------------------------------------------- geoBC[p][0:128]=W_geo[:,3:6]*xyz ; [128:256]=(W_geo[:,0:3]-W_geo[:,3:6])*xyz
__global__ __launch_bounds__(256) void geoBC_kernel(const float* __restrict__ xyz, const float* __restrict__ Wg,
                                                    float* __restrict__ geoBC) {
    int i = blockIdx.x*256 + threadIdx.x;     // over ROWS*256
    int p = i >> 8, c = i & 255, cc = c & 127;
    float x = xyz[p*3+0], y = xyz[p*3+1], z = xyz[p*3+2];
    const float* w = Wg + cc*6;
    float s;
    if (c < 128) s = (w[3]*x + w[4]*y) + w[5]*z;
    else         s = ((w[0]-w[3])*x + (w[1]-w[4])*y) + (w[2]-w[5])*z;
    geoBC[i] = s;
}

// ---------------------------------------------------------------- featAC[p][0:128]=W_feat[:,0:64]*ft[p] ; [128:256]=W_feat[:,64:128]*ft[p]
__global__ __launch_bounds__(256) void featAC_kernel(const float* __restrict__ ft, const float* __restrict__ Wf,
                                                     float* __restrict__ featAC) {
    __shared__ float fr[64];
    int p = blockIdx.x, c = threadIdx.x;
    if (c < 64) fr[c] = ft[(size_t)p*64 + c];
    __syncthreads();
    const float* w = Wf + (size_t)(c & 127)*128 + (c >> 7)*64;
    float s = 0.f;
#pragma unroll
    for (int i = 0; i < 16; i++) {
        float4 w4 = *(const float4*)&w[4*i];
        float4 f4 = *(const float4*)&fr[4*i];
        s += (w4.x*f4.x + w4.y*f4.y) + (w4.z*f4.z + w4.w*f4.w);
    }
    featAC[(size_t)p*256 + c] = s;
}

// ---------------------------------------------------------------- KNN in FLOAT64: 4 queries/block (1 per wave)
// d2 computed in f64 => true ordering (flip-proof); tie-break by smaller index (matches stable top_k).
__global__ __launch_bounds__(256) void knn_kernel(const float* __restrict__ xyz, int* __restrict__ idx) {
    __shared__ float sx[NPTS*3];
    int blk = blockIdx.x;
    int b = blk >> 9;          // 512 blocks per batch
    int g = blk & 511;
    int t = threadIdx.x;
    for (int i = t; i < NPTS*3; i += 256) sx[i] = xyz[(size_t)b*NPTS*3 + i];
    __syncthreads();
    int wave = t >> 6, lane = t & 63;
    int n = g*4 + wave;
    double qx = (double)sx[n*3], qy = (double)sx[n*3+1], qz = (double)sx[n*3+2];
    double sqn = qx*qx + qy*qy + qz*qz;
    double d[32];
#pragma unroll
    for (int i = 0; i < 32; i++) {
        int m = lane + (i << 6);
        double x = (double)sx[m*3], y = (double)sx[m*3+1], z = (double)sx[m*3+2];
        double sqm = x*x + y*y + z*z;
        double dt  = qx*x + qy*y + qz*z;
        d[i] = (sqn + sqm) - 2.0*dt;
    }
    double lv = d[0]; int li = 0;
#pragma unroll
    for (int i = 1; i < 32; i++) if (d[i] < lv) { lv = d[i]; li = i; }
    for (int kk = 0; kk < KNBR; kk++) {
        double bv = lv;
        unsigned bi = (unsigned)(lane + (li << 6));
        for (int off = 1; off < 64; off <<= 1) {
            double   ov = __shfl_xor(bv, off, 64);
            unsigned oi = __shfl_xor(bi, off, 64);
            if (ov < bv || (ov == bv && oi < bi)) { bv = ov; bi = oi; }
        }
        int m = (int)bi;
        if (lane == 0) idx[((size_t)b*NPTS + n)*KNBR + kk] = m;
        bool mine = ((m & 63) == lane);
        int slot = m >> 6;
#pragma unroll
        for (int i = 0; i < 32; i++) if (mine && slot == i) d[i] = INFINITY;
        if (mine) {
            lv = d[0]; li = 0;
#pragma unroll
            for (int i = 1; i < 32; i++) if (d[i] < lv) { lv = d[i]; li = i; }
        }
    }
}

// ---------------------------------------------------------------- geo/feat pre-act stats + per-row sign-selected extreme over K
// BN scale sign == sign(g) (rsqrt>0), so select max (g>=0) or min (g<0) now.
__global__ __launch_bounds__(256) void stats_gf(const float* __restrict__ geoBC, const float* __restrict__ featAC,
                                                const int* __restrict__ idx, const float* __restrict__ g_geo,
                                                const float* __restrict__ g_feat,
                                                float* __restrict__ sums, float* __restrict__ xsel) {
    int c = threadIdx.x;
    int cc = c & 127;
    const float* base = (c < 128) ? geoBC : featAC;
    bool wantmax = ((c < 128) ? g_geo[cc] : g_feat[cc]) >= 0.f;
    float s = 0.f, ss = 0.f;
    int r0 = blockIdx.x * 32;
    for (int r = r0; r < r0 + 32; r++) {
        int b = r >> 11;
        float ctr = base[(size_t)r*256 + 128 + cc];
        float mx = -1e30f, mn = 1e30f;
        const int* ip = idx + (size_t)r*KNBR;
        for (int kk = 0; kk < KNBR; kk++) {
            int j = ip[kk];
            float xv = ctr + base[((size_t)(b*NPTS + j))*256 + cc];
            mx = fmaxf(mx, xv); mn = fminf(mn, xv);
            s += xv; ss += xv*xv;
        }
        xsel[(size_t)r*256 + c] = wantmax ? mx : mn;
    }
    atomicAdd(&sums[c], s);
    atomicAdd(&sums[256 + c], ss);
}

__global__ void bn_finalize_gf(const float* __restrict__ sums, const float* __restrict__ g_geo,
                               const float* __restrict__ b_geo, const float* __restrict__ g_feat,
                               const float* __restrict__ b_feat, float* __restrict__ st) {
    int c = threadIdx.x;
    const float inv = 1.0f / (float)(ROWS*KNBR);
    float mean = sums[c]*inv;
    float var  = sums[256+c]*inv - mean*mean;
    float g  = (c < 128) ? g_geo[c] : g_feat[c-128];
    float bb = (c < 128) ? b_geo[c] : b_feat[c-128];
    float s = g / sqrtf(var + 1e-5f);
    st[c] = s; st[256+c] = bb - mean*s;
}

__global__ void bn_finalize(const float* __restrict__ sums, const float* __restrict__ g,
                            const float* __restrict__ b, float* __restrict__ st, float inv_cnt) {
    int c = threadIdx.x;
    float mean = sums[c]*inv_cnt;
    float var  = sums[256+c]*inv_cnt - mean*mean;
    float s = g[c] / sqrtf(var + 1e-5f);
    st[c] = s; st[256+c] = b[c] - mean*s;
}

// ---------------------------------------------------------------- feature_ = relu(affine(xsel)) ; + bn1 stats
__global__ __launch_bounds__(256) void feature_maxsel(const float* __restrict__ xsel, const float* __restrict__ st,
                                                      float* __restrict__ feat, float* __restrict__ sums_bn1) {
    int c = threadIdx.x;
    float sc = st[c], tt = st[256+c];
    float s = 0.f, ss = 0.f;
    int r0 = blockIdx.x*32;
    for (int r = r0; r < r0+32; r++) {
        size_t i = (size_t)r*256 + c;
        float y = fmaxf(fmaf(sc, xsel[i], tt), 0.f);
        feat[i] = y; s += y; ss += y*y;
    }
    atomicAdd(&sums_bn1[c], s); atomicAdd(&sums_bn1[256+c], ss);
}

// ---------------------------------------------------------------- per-channel affine (+optional relu)
__global__ void affine_kernel(const float* __restrict__ in, const float* __restrict__ st,
                              float* __restrict__ outp, int relu) {
    int i = blockIdx.x*256 + threadIdx.x;
    int c = i & 255;
    float v = fmaf(st[c], in[i], st[256+c]);
    if (relu) v = fmaxf(v, 0.f);
    outp[i] = v;
}

// ---------------------------------------------------------------- column sum/sumsq of [8192,256]
__global__ __launch_bounds__(256) void colstats(const float* __restrict__ X, float* __restrict__ sums) {
    int c = threadIdx.x; float s = 0.f, ss = 0.f;
    int r0 = blockIdx.x*32;
    for (int r = r0; r < r0+32; r++) {
        float v = X[(size_t)r*256 + c];
        s += v; ss += v*v;
    }
    atomicAdd(&sums[c], s); atomicAdd(&sums[256+c], ss);
}

// ---------------------------------------------------------------- generic NT GEMM: C[R,O] = A[R,K] * W[O,K]^T (+bias)
__global__ __launch_bounds__(256) void gemm_nt(const float* __restrict__ A, const float* __restrict__ W,
                                               float* __restrict__ C, int K, int O,
                                               const float* __restrict__ bias) {
    __shared__ float As[16][68];
    __shared__ float Ws[16][68];
    int t  = threadIdx.x;
    int tx = t & 15, ty = t >> 4;
    int r0 = blockIdx.x * 64, n0 = blockIdx.y * 64;
    float acc[4][4];
#pragma unroll
    for (int i = 0; i < 4; i++)
#pragma unroll
        for (int j = 0; j < 4; j++) acc[i][j] = 0.f;
    int lk = t & 15, lm = t >> 4;
    for (int k0 = 0; k0 < K; k0 += 16) {
#pragma unroll
        for (int i2 = 0; i2 < 4; i2++) {
            As[lk][lm + 16*i2] = A[(size_t)(r0 + lm + 16*i2)*K + k0 + lk];
            Ws[lk][lm + 16*i2] = W[(size_t)(n0 + lm + 16*i2)*K + k0 + lk];
        }
        __syncthreads();
#pragma unroll
        for (int kq = 0; kq < 16; kq++) {
            float4 a  = *(const float4*)&As[kq][4*ty];
            float4 b4 = *(const float4*)&Ws[kq][4*tx];
            float av[4] = {a.x, a.y, a.z, a.w};
            float bv[4] = {b4.x, b4.y, b4.z, b4.w};
#pragma unroll
            for (int i = 0; i < 4; i++)
#pragma unroll
                for (int j = 0; j < 4; j++) acc[i][j] = fmaf(av[i], bv[j], acc[i][j]);
        }
        __syncthreads();
    }
#pragma unroll
    for (int i = 0; i < 4; i++)
#pragma unroll
        for (int j = 0; j < 4; j++) {
            float vv = acc[i][j];
            if (bias) vv += bias[n0 + 4*tx + j];
            C[(size_t)(r0 + 4*ty + i)*O + n0 + 4*tx + j] = vv;
        }
}

// ---------------------------------------------------------------- flash attention (fp32), 64q x 64k tiles
__global__ __launch_bounds__(256) void attn_kernel(const float* __restrict__ q, const float* __restrict__ k,
                                                   const float* __restrict__ v, float* __restrict__ obuf) {
    __shared__ float Qs[64][68];   // [kk][r]
    __shared__ float Ks[64][68];   // [kk][c]
    __shared__ float Vs[64][68];   // [mm][c]
    __shared__ float Ps[64][68];   // [mm][r]
    int rt = blockIdx.x, h = blockIdx.y, b = blockIdx.z;
    int r0 = rt*64;
    int t = threadIdx.x;
    int tx = t & 15, ty = t >> 4;
    size_t hb = ((size_t)b*NPTS)*COUT + h*DSH;
    {
        int kk = t & 63, rg = t >> 6;
        for (int r = rg; r < 64; r += 4)
            Qs[kk][r] = q[hb + (size_t)(r0 + r)*COUT + kk];
    }
    float mrun[4], lrun[4], oacc[4][4];
#pragma unroll
    for (int i = 0; i < 4; i++) {
        mrun[i] = -1e30f; lrun[i] = 0.f;
#pragma unroll
        for (int j = 0; j < 4; j++) oacc[i][j] = 0.f;
    }
    for (int m0 = 0; m0 < NPTS; m0 += 64) {
        {
            int kk = t & 63, cg = t >> 6;
            for (int c = cg; c < 64; c += 4)
                Ks[kk][c] = k[hb + (size_t)(m0 + c)*COUT + kk];
            for (int mm = cg; mm < 64; mm += 4)
                Vs[mm][kk] = v[hb + (size_t)(m0 + mm)*COUT + kk];
        }
        __syncthreads();
        float sacc[4][4];
#pragma unroll
        for (int i = 0; i < 4; i++)
#pragma unroll
            for (int j = 0; j < 4; j++) sacc[i][j] = 0.f;
        for (int kk = 0; kk < 64; kk++) {
            float4 a  = *(const float4*)&Qs[kk][4*ty];
            float4 bb = *(const float4*)&Ks[kk][4*tx];
            float av[4] = {a.x, a.y, a.z, a.w};
            float bv[4] = {bb.x, bb.y, bb.z, bb.w};
#pragma unroll
            for (int i = 0; i < 4; i++)
#pragma unroll
                for (int j = 0; j < 4; j++) sacc[i][j] = fmaf(av[i], bv[j], sacc[i][j]);
        }
        float pmat[4][4];
#pragma unroll
        for (int i = 0; i < 4; i++) {
            float rmax = fmaxf(fmaxf(sacc[i][0], sacc[i][1]), fmaxf(sacc[i][2], sacc[i][3]));
            for (int msk = 1; msk < 16; msk <<= 1) rmax = fmaxf(rmax, __shfl_xor(rmax, msk, 64));
            float mnew = fmaxf(mrun[i], rmax);
            float alpha = __expf(mrun[i] - mnew);
            float rs = 0.f;
#pragma unroll
            for (int j = 0; j < 4; j++) { pmat[i][j] = __expf(sacc[i][j] - mnew); rs += pmat[i][j]; }
            for (int msk = 1; msk < 16; msk <<= 1) rs += __shfl_xor(rs, msk, 64);
            lrun[i] = lrun[i]*alpha + rs;
            mrun[i] = mnew;
#pragma unroll
            for (int j = 0; j < 4; j++) oacc[i][j] *= alpha;
        }
#pragma unroll
        for (int j = 0; j < 4; j++) {
            float4 pv = make_float4(pmat[0][j], pmat[1][j], pmat[2][j], pmat[3][j]);
            *(float4*)&Ps[4*tx + j][4*ty] = pv;
        }
        __syncthreads();
        for (int mm = 0; mm < 64; mm++) {
            float4 a  = *(const float4*)&Ps[mm][4*ty];
            float4 bb = *(const float4*)&Vs[mm][4*tx];
            float av[4] = {a.x, a.y, a.z, a.w};
            float bv[4] = {bb.x, bb.y, bb.z, bb.w};
#pragma unroll
            for (int i = 0; i < 4; i++)
#pragma unroll
                for (int j = 0; j < 4; j++) oacc[i][j] = fmaf(av[i], bv[j], oacc[i][j]);
        }
        __syncthreads();
    }
    size_t ob = ((size_t)b*NPTS + r0)*(NHEADS*WCH) + h*WCH;
#pragma unroll
    for (int i = 0; i < 4; i++) {
        float invl = 1.f / lrun[i];
#pragma unroll
        for (int j = 0; j < 4; j++)
            obuf[ob + (size_t)(4*ty + i)*(NHEADS*WCH) + 4*tx + j] = oacc[i][j]*invl;
    }
}

// ---------------------------------------------------------------- residual + LayerNorm -> feature__ (in place) and y
__global__ __launch_bounds__(256) void ln_kernel(float* __restrict__ fus, const float* __restrict__ feature,
                                                 const float* __restrict__ g_ln, const float* __restrict__ b_ln,
                                                 float* __restrict__ y) {
    int r = blockIdx.x, c = threadIdx.x;
    size_t i = (size_t)r*256 + c;
    float v = fus[i] + feature[i];
    float s = v, ss = v*v;
    for (int m = 1; m < 64; m <<= 1) { s += __shfl_xor(s, m, 64); ss += __shfl_xor(ss, m, 64); }
    __shared__ float red[8];
    int wave = c >> 6, lane = c & 63;
    if (lane == 0) { red[wave] = s; red[4+wave] = ss; }
    __syncthreads();
    s  = red[0]+red[1]+red[2]+red[3];
    ss = red[4]+red[5]+red[6]+red[7];
    float mean = s * (1.f/256.f);
    float var  = ss * (1.f/256.f) - mean*mean;
    float rin  = 1.f/sqrtf(var + 1e-5f);
    fus[i] = v;
    y[i] = (v - mean)*rin*g_ln[c] + b_ln[c];
}

// ---------------------------------------------------------------- out[b][c][n] = feature__[b,n,c] + mlp[b,n,c]
__global__ __launch_bounds__(256) void out_kernel(const float* __restrict__ fpp, const float* __restrict__ mlp,
                                                  float* __restrict__ outp) {
    __shared__ float tile[64][65];
    int nt = blockIdx.x, ct = blockIdx.y, b = blockIdx.z;
    int t = threadIdx.x;
    for (int e = t; e < 4096; e += 256) {
        int n = e >> 6, c = e & 63;
        size_t i = (size_t)(b*NPTS + nt*64 + n)*256 + ct*64 + c;
        tile[c][n] = fpp[i] + mlp[i];
    }
    __syncthreads();
    for (int e = t; e < 4096; e += 256) {
        int c = e >> 6, n = e & 63;
        outp[((size_t)b*256 + ct*64 + c)*NPTS + nt*64 + n] = tile[c][n];
    }
}

// ================================================================ host
extern "C" void kernel_launch(void* const* d_in, const int* in_sizes, int n_in,
                              void* d_out, int out_size, void* d_ws, size_t ws_size,
                              hipStream_t stream) {
    const float* xyz    = (const float*)d_in[0];
    const float* f      = (const float*)d_in[1];
    const float* W_geo  = (const float*)d_in[2];
    const float* g_geo  = (const float*)d_in[3];
    const float* b_geo  = (const float*)d_in[4];
    const float* W_feat = (const float*)d_in[5];
    const float* g_feat = (const float*)d_in[6];
    const float* b_feat = (const float*)d_in[7];
    const float* g_bn   = (const float*)d_in[8];
    const float* b_bn   = (const float*)d_in[9];
    const float* W_q    = (const float*)d_in[10];
    const float* g_q    = (const float*)d_in[11];
    const float* b_q    = (const float*)d_in[12];
    const float* W_k    = (const float*)d_in[13];
    const float* g_k    = (const float*)d_in[14];
    const float* b_k    = (const float*)d_in[15];
    const float* W_v    = (const float*)d_in[16];
    const float* g_v    = (const float*)d_in[17];
    const float* b_v    = (const float*)d_in[18];
    const float* W_fus  = (const float*)d_in[19];
    const float* bias_fus = (const float*)d_in[20];
    const float* g_fus  = (const float*)d_in[21];
    const float* b_fus  = (const float*)d_in[22];
    const float* g_ln   = (const float*)d_in[23];
    const float* b_ln   = (const float*)d_in[24];
    const float* W_mlp  = (const float*)d_in[25];
    const float* bias_mlp = (const float*)d_in[26];

    float* ws = (float*)d_ws;
    const size_t MBF = 262144;            // floats per MiB
    // Compact liveness plan — peak 49 MiB.
    float* SUMS   = ws;
    float* ST     = ws + 4096;
    int*   IDX    = (int*)(ws + 16384);
    float* FT     = ws + 1*MBF;
    float* A      = ws + 3*MBF;
    float* X      = ws + 11*MBF;
    float* OBUF   = ws + 11*MBF;
    float* CSEL   = ws + 19*MBF;
    float* QB     = ws + 25*MBF;
    float* KBUF   = ws + 33*MBF;
    float* VBUF   = ws + 41*MBF;

    float* S_GF  = SUMS;        float* T_GF  = ST;
    float* S_BN1 = SUMS + 512;  float* T_BN1 = ST + 512;
    float* S_Q   = SUMS + 1024; float* T_Q   = ST + 1024;
    float* S_K   = SUMS + 1536; float* T_K   = ST + 1536;
    float* S_V   = SUMS + 2048; float* T_V   = ST + 2048;
    float* S_FUS = SUMS + 2560; float* T_FUS = ST + 2560;

    hipMemsetAsync(SUMS, 0, 6*512*sizeof(float), stream);

    transpose_f<<<NB*32, 256, 0, stream>>>(f, FT);
    geoBC_kernel<<<ROWS, 256, 0, stream>>>(xyz, W_geo, A);
    featAC_kernel<<<ROWS, 256, 0, stream>>>(FT, W_feat, X);
    knn_kernel<<<ROWS/4, 256, 0, stream>>>(xyz, IDX);

    stats_gf<<<256, 256, 0, stream>>>(A, X, IDX, g_geo, g_feat, S_GF, CSEL);
    bn_finalize_gf<<<1, 256, 0, stream>>>(S_GF, g_geo, b_geo, g_feat, b_feat, T_GF);
    feature_maxsel<<<256, 256, 0, stream>>>(CSEL, T_GF, A, S_BN1);   // feature_ -> A
    bn_finalize<<<1, 256, 0, stream>>>(S_BN1, g_bn, b_bn, T_BN1, 1.0f/(float)ROWS);
    affine_kernel<<<ROWS, 256, 0, stream>>>(A, T_BN1, X, 0);         // x -> X

    gemm_nt<<<dim3(ROWS/64, 4), 256, 0, stream>>>(X, W_q, QB,   256, 256, nullptr);
    gemm_nt<<<dim3(ROWS/64, 4), 256, 0, stream>>>(X, W_k, KBUF, 256, 256, nullptr);
    gemm_nt<<<dim3(ROWS/64, 4), 256, 0, stream>>>(X, W_v, VBUF, 256, 256, nullptr);
    colstats<<<256, 256, 0, stream>>>(QB,   S_Q);
    colstats<<<256, 256, 0, stream>>>(KBUF, S_K);
    colstats<<<256, 256, 0, stream>>>(VBUF, S_V);
    bn_finalize<<<1, 256, 0, stream>>>(S_Q, g_q, b_q, T_Q, 1.0f/(float)ROWS);
    bn_finalize<<<1, 256, 0, stream>>>(S_K, g_k, b_k, T_K, 1.0f/(float)ROWS);
    bn_finalize<<<1, 256, 0, stream>>>(S_V, g_v, b_v, T_V, 1.0f/(float)ROWS);
    affine_kernel<<<ROWS, 256, 0, stream>>>(QB,   T_Q, QB,   1);
    affine_kernel<<<ROWS, 256, 0, stream>>>(KBUF, T_K, KBUF, 1);
    affine_kernel<<<ROWS, 256, 0, stream>>>(VBUF, T_V, VBUF, 1);

    attn_kernel<<<dim3(NPTS/64, NHEADS, NB), 256, 0, stream>>>(QB, KBUF, VBUF, OBUF);  // OBUF over x

    gemm_nt<<<dim3(ROWS/64, 4), 256, 0, stream>>>(OBUF, W_fus, QB, 448, 256, bias_fus); // fus_pre -> QB slot
    colstats<<<256, 256, 0, stream>>>(QB, S_FUS);
    bn_finalize<<<1, 256, 0, stream>>>(S_FUS, g_fus, b_fus, T_FUS, 1.0f/(float)ROWS);
    affine_kernel<<<ROWS, 256, 0, stream>>>(QB, T_FUS, QB, 1);       // fus

    ln_kernel<<<ROWS, 256, 0, stream>>>(QB, A, g_ln, b_ln, KBUF);    // feature__ in QB, y in KBUF
    gemm_nt<<<dim3(ROWS/64, 4), 256, 0, stream>>>(KBUF, W_mlp, VBUF, 256, 256, bias_mlp);
    out_kernel<<<dim3(NPTS/64, 4, NB), 256, 0, stream>>>(QB, VBUF, (float*)d_out);
}

// Round 6
// 706.876 us; speedup vs baseline: 1.6179x; 1.6179x over previous
//
#include <hip/hip_runtime.h>
#include <math.h>

#define NB    4
#define NPTS  2048
#define ROWS  (NB*NPTS)   // 8192
#define CIN   64
#define COUT  256
#define KNBR  21
#define NHEADS 7
#define WCH   64
#define DSH   32

typedef __attribute__((ext_vector_type(8))) short short8;
typedef __attribute__((ext_vector_type(4))) float floatx4;

__device__ __forceinline__ ushort f2bf(float x) {
    unsigned u = __float_as_uint(x);
    u += 0x7fffu + ((u >> 16) & 1u);   // RNE
    return (ushort)(u >> 16);
}

// ---------------------------------------------------------------- transpose f [B,64,2048] -> ft [B*2048,64]
__global__ __launch_bounds__(256) void transpose_f(const float* __restrict__ f, float* __restrict__ ft) {
    __shared__ float tile[64][65];
    int b  = blockIdx.x >> 5;
    int nt = blockIdx.x & 31;
    int t  = threadIdx.x;
    for (int e = t; e < 4096; e += 256) {
        int cc = e >> 6, nn = e & 63;
        tile[cc][nn] = f[(size_t)b*CIN*NPTS + (size_t)cc*NPTS + nt*64 + nn];
    }
    __syncthreads();
    for (int e = t; e < 4096; e += 256) {
        int nn = e >> 6, cc = e & 63;
        ft[((size_t)(b*NPTS + nt*64 + nn))*64 + cc] = tile[cc][nn];
    }
}

// ---------------------------------------------------------------- geoBC
__global__ __launch_bounds__(256) void geoBC_kernel(const float* __restrict__ xyz, const float* __restrict__ Wg,
                                                    float* __restrict__ geoBC) {
    int i = blockIdx.x*256 + threadIdx.x;
    int p = i >> 8, c = i & 255, cc = c & 127;
    float x = xyz[p*3+0], y = xyz[p*3+1], z = xyz[p*3+2];
    const float* w = Wg + cc*6;
    float s;
    if (c < 128) s = (w[3]*x + w[4]*y) + w[5]*z;
    else         s = ((w[0]-w[3])*x + (w[1]-w[4])*y) + (w[2]-w[5])*z;
    geoBC[i] = s;
}

// ---------------------------------------------------------------- featAC
__global__ __launch_bounds__(256) void featAC_kernel(const float* __restrict__ ft, const float* __restrict__ Wf,
                                                     float* __restrict__ featAC) {
    __shared__ float fr[64];
    int p = blockIdx.x, c = threadIdx.x;
    if (c < 64) fr[c] = ft[(size_t)p*64 + c];
    __syncthreads();
    const float* w = Wf + (size_t)(c & 127)*128 + (c >> 7)*64;
    float s = 0.f;
#pragma unroll
    for (int i = 0; i < 16; i++) {
        float4 w4 = *(const float4*)&w[4*i];
        float4 f4 = *(const float4*)&fr[4*i];
        s += (w4.x*f4.x + w4.y*f4.y) + (w4.z*f4.z + w4.w*f4.w);
    }
    featAC[(size_t)p*256 + c] = s;
}

// ---------------------------------------------------------------- KNN in FLOAT64 (exact ordering)
__global__ __launch_bounds__(256) void knn_kernel(const float* __restrict__ xyz, int* __restrict__ idx) {
    __shared__ float sx[NPTS*3];
    int blk = blockIdx.x;
    int b = blk >> 9;
    int g = blk & 511;
    int t = threadIdx.x;
    for (int i = t; i < NPTS*3; i += 256) sx[i] = xyz[(size_t)b*NPTS*3 + i];
    __syncthreads();
    int wave = t >> 6, lane = t & 63;
    int n = g*4 + wave;
    double qx = (double)sx[n*3], qy = (double)sx[n*3+1], qz = (double)sx[n*3+2];
    double sqn = qx*qx + qy*qy + qz*qz;
    double d[32];
#pragma unroll
    for (int i = 0; i < 32; i++) {
        int m = lane + (i << 6);
        double x = (double)sx[m*3], y = (double)sx[m*3+1], z = (double)sx[m*3+2];
        double sqm = x*x + y*y + z*z;
        double dt  = qx*x + qy*y + qz*z;
        d[i] = (sqn + sqm) - 2.0*dt;
    }
    double lv = d[0]; int li = 0;
#pragma unroll
    for (int i = 1; i < 32; i++) if (d[i] < lv) { lv = d[i]; li = i; }
    for (int kk = 0; kk < KNBR; kk++) {
        double bv = lv;
        unsigned bi = (unsigned)(lane + (li << 6));
        for (int off = 1; off < 64; off <<= 1) {
            double   ov = __shfl_xor(bv, off, 64);
            unsigned oi = __shfl_xor(bi, off, 64);
            if (ov < bv || (ov == bv && oi < bi)) { bv = ov; bi = oi; }
        }
        int m = (int)bi;
        if (lane == 0) idx[((size_t)b*NPTS + n)*KNBR + kk] = m;
        bool mine = ((m & 63) == lane);
        int slot = m >> 6;
#pragma unroll
        for (int i = 0; i < 32; i++) if (mine && slot == i) d[i] = INFINITY;
        if (mine) {
            lv = d[0]; li = 0;
#pragma unroll
            for (int i = 1; i < 32; i++) if (d[i] < lv) { lv = d[i]; li = i; }
        }
    }
}

// ---------------------------------------------------------------- stats + sign-selected extreme over K
__global__ __launch_bounds__(256) void stats_gf(const float* __restrict__ geoBC, const float* __restrict__ featAC,
                                                const int* __restrict__ idx, const float* __restrict__ g_geo,
                                                const float* __restrict__ g_feat,
                                                float* __restrict__ sums, float* __restrict__ xsel) {
    int c = threadIdx.x;
    int cc = c & 127;
    const float* base = (c < 128) ? geoBC : featAC;
    bool wantmax = ((c < 128) ? g_geo[cc] : g_feat[cc]) >= 0.f;
    float s = 0.f, ss = 0.f;
    int r0 = blockIdx.x * 32;
    for (int r = r0; r < r0 + 32; r++) {
        int b = r >> 11;
        float ctr = base[(size_t)r*256 + 128 + cc];
        float mx = -1e30f, mn = 1e30f;
        const int* ip = idx + (size_t)r*KNBR;
        for (int kk = 0; kk < KNBR; kk++) {
            int j = ip[kk];
            float xv = ctr + base[((size_t)(b*NPTS + j))*256 + cc];
            mx = fmaxf(mx, xv); mn = fminf(mn, xv);
            s += xv; ss += xv*xv;
        }
        xsel[(size_t)r*256 + c] = wantmax ? mx : mn;
    }
    atomicAdd(&sums[c], s);
    atomicAdd(&sums[256 + c], ss);
}

__global__ void bn_finalize_gf(const float* __restrict__ sums, const float* __restrict__ g_geo,
                               const float* __restrict__ b_geo, const float* __restrict__ g_feat,
                               const float* __restrict__ b_feat, float* __restrict__ st) {
    int c = threadIdx.x;
    const float inv = 1.0f / (float)(ROWS*KNBR);
    float mean = sums[c]*inv;
    float var  = sums[256+c]*inv - mean*mean;
    float g  = (c < 128) ? g_geo[c] : g_feat[c-128];
    float bb = (c < 128) ? b_geo[c] : b_feat[c-128];
    float s = g / sqrtf(var + 1e-5f);
    st[c] = s; st[256+c] = bb - mean*s;
}

__global__ void bn_finalize(const float* __restrict__ sums, const float* __restrict__ g,
                            const float* __restrict__ b, float* __restrict__ st, float inv_cnt) {
    int c = threadIdx.x;
    float mean = sums[c]*inv_cnt;
    float var  = sums[256+c]*inv_cnt - mean*mean;
    float s = g[c] / sqrtf(var + 1e-5f);
    st[c] = s; st[256+c] = b[c] - mean*s;
}

// ---------------------------------------------------------------- feature_ = relu(affine(xsel)) ; + bn1 stats
__global__ __launch_bounds__(256) void feature_maxsel(const float* __restrict__ xsel, const float* __restrict__ st,
                                                      float* __restrict__ feat, float* __restrict__ sums_bn1) {
    int c = threadIdx.x;
    float sc = st[c], tt = st[256+c];
    float s = 0.f, ss = 0.f;
    int r0 = blockIdx.x*32;
    for (int r = r0; r < r0+32; r++) {
        size_t i = (size_t)r*256 + c;
        float y = fmaxf(fmaf(sc, xsel[i], tt), 0.f);
        feat[i] = y; s += y; ss += y*y;
    }
    atomicAdd(&sums_bn1[c], s); atomicAdd(&sums_bn1[256+c], ss);
}

// ---------------------------------------------------------------- per-channel affine (+optional relu), fp32 out
__global__ void affine_kernel(const float* __restrict__ in, const float* __restrict__ st,
                              float* __restrict__ outp, int relu) {
    int i = blockIdx.x*256 + threadIdx.x;
    int c = i & 255;
    float v = fmaf(st[c], in[i], st[256+c]);
    if (relu) v = fmaxf(v, 0.f);
    outp[i] = v;
}

// ---------------------------------------------------------------- affine + relu, bf16 out (for q/k/v)
__global__ void affine_bf16_kernel(const float* __restrict__ in, const float* __restrict__ st,
                                   ushort* __restrict__ outp) {
    int i = blockIdx.x*256 + threadIdx.x;
    int c = i & 255;
    float v = fmaxf(fmaf(st[c], in[i], st[256+c]), 0.f);
    outp[i] = f2bf(v);
}

// ---------------------------------------------------------------- column sum/sumsq of [8192,256]
__global__ __launch_bounds__(256) void colstats(const float* __restrict__ X, float* __restrict__ sums) {
    int c = threadIdx.x; float s = 0.f, ss = 0.f;
    int r0 = blockIdx.x*32;
    for (int r = r0; r < r0+32; r++) {
        float v = X[(size_t)r*256 + c];
        s += v; ss += v*v;
    }
    atomicAdd(&sums[c], s); atomicAdd(&sums[256+c], ss);
}

// ---------------------------------------------------------------- generic NT GEMM (fp32 VALU)
__global__ __launch_bounds__(256) void gemm_nt(const float* __restrict__ A, const float* __restrict__ W,
                                               float* __restrict__ C, int K, int O,
                                               const float* __restrict__ bias) {
    __shared__ float As[16][68];
    __shared__ float Ws[16][68];
    int t  = threadIdx.x;
    int tx = t & 15, ty = t >> 4;
    int r0 = blockIdx.x * 64, n0 = blockIdx.y * 64;
    float acc[4][4];
#pragma unroll
    for (int i = 0; i < 4; i++)
#pragma unroll
        for (int j = 0; j < 4; j++) acc[i][j] = 0.f;
    int lk = t & 15, lm = t >> 4;
    for (int k0 = 0; k0 < K; k0 += 16) {
#pragma unroll
        for (int i2 = 0; i2 < 4; i2++) {
            As[lk][lm + 16*i2] = A[(size_t)(r0 + lm + 16*i2)*K + k0 + lk];
            Ws[lk][lm + 16*i2] = W[(size_t)(n0 + lm + 16*i2)*K + k0 + lk];
        }
        __syncthreads();
#pragma unroll
        for (int kq = 0; kq < 16; kq++) {
            float4 a  = *(const float4*)&As[kq][4*ty];
            float4 b4 = *(const float4*)&Ws[kq][4*tx];
            float av[4] = {a.x, a.y, a.z, a.w};
            float bv[4] = {b4.x, b4.y, b4.z, b4.w};
#pragma unroll
            for (int i = 0; i < 4; i++)
#pragma unroll
                for (int j = 0; j < 4; j++) acc[i][j] = fmaf(av[i], bv[j], acc[i][j]);
        }
        __syncthreads();
    }
#pragma unroll
    for (int i = 0; i < 4; i++)
#pragma unroll
        for (int j = 0; j < 4; j++) {
            float vv = acc[i][j];
            if (bias) vv += bias[n0 + 4*tx + j];
            C[(size_t)(r0 + 4*ty + i)*O + n0 + 4*tx + j] = vv;
        }
}

// ---------------------------------------------------------------- MFMA bf16 flash attention
// 64 q-rows per block, 4 waves: wave w owns rows 16w..16w+15.
// LDS: K [key][dim], Vt [dim][key], P [row][key], all bf16 with 16B-chunk XOR swizzle.
__global__ __launch_bounds__(256) void attn_mfma(const ushort* __restrict__ q, const ushort* __restrict__ k,
                                                 const ushort* __restrict__ v, float* __restrict__ obuf) {
    __shared__ ushort Ksh[64*64];
    __shared__ ushort Vts[64*64];
    __shared__ ushort Psh[64*64];
    int rt = blockIdx.x, h = blockIdx.y, b = blockIdx.z;
    int r0 = rt*64;
    int t = threadIdx.x;
    int w = t >> 6, lane = t & 63;
    int r15 = lane & 15, quad = lane >> 4;
    size_t rowbase = (size_t)b*NPTS;
    int hoff = h*DSH;

    // Q fragments: aq[s] = Q[16w+r15][32s + 8*quad .. +7]  (A-layout: m=lane&15, k=quad*8+j)
    short8 aq[2];
    {
        const ushort* qp = q + (rowbase + r0 + 16*w + r15)*COUT + hoff;
#pragma unroll
        for (int s = 0; s < 2; s++)
            aq[s] = *(const short8*)(qp + 32*s + 8*quad);
    }
    floatx4 zero4 = {0.f, 0.f, 0.f, 0.f};
    floatx4 oacc[4];
    float mrun[4], lrun[4];
#pragma unroll
    for (int i = 0; i < 4; i++) { oacc[i] = zero4; mrun[i] = -1e30f; lrun[i] = 0.f; }

    for (int m0 = 0; m0 < NPTS; m0 += 64) {
        // ---- stage K (vector) and V^T (scatter) ----
#pragma unroll
        for (int rep = 0; rep < 2; rep++) {
            int e = t + rep*256;            // 0..511 chunk id
            int key = e >> 3, c = e & 7;
            const ushort* ksrc = k + (rowbase + m0 + key)*COUT + hoff + 8*c;
            uint4 kv = *(const uint4*)ksrc;
            *(uint4*)&Ksh[key*64 + ((c ^ (key & 7)) << 3)] = kv;
            const ushort* vsrc = v + (rowbase + m0 + key)*COUT + hoff + 8*c;
            uint4 vv = *(const uint4*)vsrc;
            unsigned words[4] = {vv.x, vv.y, vv.z, vv.w};
#pragma unroll
            for (int jj = 0; jj < 4; jj++) {
                int d0 = 8*c + 2*jj, d1 = d0 + 1;
                Vts[d0*64 + (((key >> 3) ^ (d0 & 7)) << 3) + (key & 7)] = (ushort)(words[jj] & 0xffffu);
                Vts[d1*64 + (((key >> 3) ^ (d1 & 7)) << 3) + (key & 7)] = (ushort)(words[jj] >> 16);
            }
        }
        __syncthreads();

        // ---- S = Q K^T  (4 col-tiles x 2 k-steps) ----
        floatx4 sacc[4];
#pragma unroll
        for (int tt = 0; tt < 4; tt++) sacc[tt] = zero4;
#pragma unroll
        for (int tt = 0; tt < 4; tt++) {
            int key = 16*tt + r15;
#pragma unroll
            for (int s = 0; s < 2; s++) {
                int c = 4*s + quad;
                short8 kf = *(const short8*)&Ksh[key*64 + ((c ^ (key & 7)) << 3)];
                sacc[tt] = __builtin_amdgcn_mfma_f32_16x16x32_bf16(aq[s], kf, sacc[tt], 0, 0, 0);
            }
        }

        // ---- online softmax (rows = quad*4+reg; cols across tt & r15-group) ----
        float pmat[4][4];  // [tt][reg]
#pragma unroll
        for (int reg = 0; reg < 4; reg++) {
            float rmax = fmaxf(fmaxf(sacc[0][reg], sacc[1][reg]), fmaxf(sacc[2][reg], sacc[3][reg]));
#pragma unroll
            for (int msk = 1; msk < 16; msk <<= 1) rmax = fmaxf(rmax, __shfl_xor(rmax, msk, 64));
            float mnew = fmaxf(mrun[reg], rmax);
            float alpha = __expf(mrun[reg] - mnew);
            float rs = 0.f;
#pragma unroll
            for (int tt = 0; tt < 4; tt++) {
                float p = __expf(sacc[tt][reg] - mnew);
                pmat[tt][reg] = p; rs += p;
            }
#pragma unroll
            for (int msk = 1; msk < 16; msk <<= 1) rs += __shfl_xor(rs, msk, 64);
            lrun[reg] = lrun[reg]*alpha + rs;
            mrun[reg] = mnew;
#pragma unroll
            for (int td = 0; td < 4; td++) oacc[td][reg] *= alpha;
        }

        // ---- write P (bf16, swizzled), rows 16w..16w+15 per wave ----
        int rbase = 16*w + 4*quad;
#pragma unroll
        for (int reg = 0; reg < 4; reg++) {
            int rr = rbase + reg;
#pragma unroll
            for (int tt = 0; tt < 4; tt++) {
                int key = 16*tt + r15;
                Psh[rr*64 + ((((key >> 3) ^ (rr & 7))) << 3) + (key & 7)] = f2bf(pmat[tt][reg]);
            }
        }
        __syncthreads();   // order P stores vs vector P loads

        // ---- O += P V ----
        int rowp = 16*w + r15;
#pragma unroll
        for (int s = 0; s < 2; s++) {
            int kc = 4*s + quad;
            short8 pf = *(const short8*)&Psh[rowp*64 + ((kc ^ (rowp & 7)) << 3)];
#pragma unroll
            for (int td = 0; td < 4; td++) {
                int dim = 16*td + r15;
                short8 vf = *(const short8*)&Vts[dim*64 + ((kc ^ (dim & 7)) << 3)];
                oacc[td] = __builtin_amdgcn_mfma_f32_16x16x32_bf16(pf, vf, oacc[td], 0, 0, 0);
            }
        }
        __syncthreads();   // protect K/Vt/P before next staging
    }

    // ---- epilogue ----
    int grow = r0 + 16*w + 4*quad;
    size_t ob = (rowbase + grow)*(size_t)(NHEADS*WCH) + h*WCH;
#pragma unroll
    for (int reg = 0; reg < 4; reg++) {
        float invl = 1.f / lrun[reg];
#pragma unroll
        for (int td = 0; td < 4; td++)
            obuf[ob + (size_t)reg*(NHEADS*WCH) + 16*td + r15] = oacc[td][reg]*invl;
    }
}

// ---------------------------------------------------------------- residual + LayerNorm
__global__ __launch_bounds__(256) void ln_kernel(float* __restrict__ fus, const float* __restrict__ feature,
                                                 const float* __restrict__ g_ln, const float* __restrict__ b_ln,
                                                 float* __restrict__ y) {
    int r = blockIdx.x, c = threadIdx.x;
    size_t i = (size_t)r*256 + c;
    float v = fus[i] + feature[i];
    float s = v, ss = v*v;
    for (int m = 1; m < 64; m <<= 1) { s += __shfl_xor(s, m, 64); ss += __shfl_xor(ss, m, 64); }
    __shared__ float red[8];
    int wave = c >> 6, lane = c & 63;
    if (lane == 0) { red[wave] = s; red[4+wave] = ss; }
    __syncthreads();
    s  = red[0]+red[1]+red[2]+red[3];
    ss = red[4]+red[5]+red[6]+red[7];
    float mean = s * (1.f/256.f);
    float var  = ss * (1.f/256.f) - mean*mean;
    float rin  = 1.f/sqrtf(var + 1e-5f);
    fus[i] = v;
    y[i] = (v - mean)*rin*g_ln[c] + b_ln[c];
}

// ---------------------------------------------------------------- out[b][c][n] = feature__ + mlp (transposed)
__global__ __launch_bounds__(256) void out_kernel(const float* __restrict__ fpp, const float* __restrict__ mlp,
                                                  float* __restrict__ outp) {
    __shared__ float tile[64][65];
    int nt = blockIdx.x, ct = blockIdx.y, b = blockIdx.z;
    int t = threadIdx.x;
    for (int e = t; e < 4096; e += 256) {
        int n = e >> 6, c = e & 63;
        size_t i = (size_t)(b*NPTS + nt*64 + n)*256 + ct*64 + c;
        tile[c][n] = fpp[i] + mlp[i];
    }
    __syncthreads();
    for (int e = t; e < 4096; e += 256) {
        int c = e >> 6, n = e & 63;
        outp[((size_t)b*256 + ct*64 + c)*NPTS + nt*64 + n] = tile[c][n];
    }
}

// ================================================================ host
extern "C" void kernel_launch(void* const* d_in, const int* in_sizes, int n_in,
                              void* d_out, int out_size, void* d_ws, size_t ws_size,
                              hipStream_t stream) {
    const float* xyz    = (const float*)d_in[0];
    const float* f      = (const float*)d_in[1];
    const float* W_geo  = (const float*)d_in[2];
    const float* g_geo  = (const float*)d_in[3];
    const float* b_geo  = (const float*)d_in[4];
    const float* W_feat = (const float*)d_in[5];
    const float* g_feat = (const float*)d_in[6];
    const float* b_feat = (const float*)d_in[7];
    const float* g_bn   = (const float*)d_in[8];
    const float* b_bn   = (const float*)d_in[9];
    const float* W_q    = (const float*)d_in[10];
    const float* g_q    = (const float*)d_in[11];
    const float* b_q    = (const float*)d_in[12];
    const float* W_k    = (const float*)d_in[13];
    const float* g_k    = (const float*)d_in[14];
    const float* b_k    = (const float*)d_in[15];
    const float* W_v    = (const float*)d_in[16];
    const float* g_v    = (const float*)d_in[17];
    const float* b_v    = (const float*)d_in[18];
    const float* W_fus  = (const float*)d_in[19];
    const float* bias_fus = (const float*)d_in[20];
    const float* g_fus  = (const float*)d_in[21];
    const float* b_fus  = (const float*)d_in[22];
    const float* g_ln   = (const float*)d_in[23];
    const float* b_ln   = (const float*)d_in[24];
    const float* W_mlp  = (const float*)d_in[25];
    const float* bias_mlp = (const float*)d_in[26];

    float* ws = (float*)d_ws;
    const size_t MBF = 262144;  // floats per MiB
    // CORRECTED liveness plan (bf16 buffers are 4 MiB each, not 2!). Peak 45 MiB.
    //  [0,1)    control + IDX
    //  [1,3)    FT
    //  [3,11)   A: geoBC -> feature_ (live until ln)
    //  [11,19)  CSEL -> QBF -> FUS/feature__
    //  [19,27)  X: featAC -> x -> {QB16 [19,23), KB16 [23,27)} -> YB (y)
    //  [27,35)  KBF -> VB16 [27,31) -> MLP
    //  [35,43)  VBF (dead before OBUF written past 35)
    //  [31,45)  OBUF [8192,448] fp32 (after VBF dead)
    float* SUMS  = ws;
    float* ST    = ws + 4096;
    int*   IDX   = (int*)(ws + 16384);
    float* FT    = ws + 1*MBF;
    float* A     = ws + 3*MBF;
    float* CSEL  = ws + 11*MBF;
    float* QBF   = ws + 11*MBF;
    float* FUS   = ws + 11*MBF;
    float* X     = ws + 19*MBF;
    ushort* QB16 = (ushort*)(ws + 19*MBF);   // 4 MiB
    ushort* KB16 = (ushort*)(ws + 23*MBF);   // 4 MiB
    float* YB    = ws + 19*MBF;
    float* KBF   = ws + 27*MBF;
    ushort* VB16 = (ushort*)(ws + 27*MBF);   // 4 MiB
    float* MLP   = ws + 27*MBF;
    float* VBF   = ws + 35*MBF;
    float* OBUF  = ws + 31*MBF;              // 14 MiB -> [31,45)

    float* S_GF  = SUMS;        float* T_GF  = ST;
    float* S_BN1 = SUMS + 512;  float* T_BN1 = ST + 512;
    float* S_Q   = SUMS + 1024; float* T_Q   = ST + 1024;
    float* S_K   = SUMS + 1536; float* T_K   = ST + 1536;
    float* S_V   = SUMS + 2048; float* T_V   = ST + 2048;
    float* S_FUS = SUMS + 2560; float* T_FUS = ST + 2560;

    hipMemsetAsync(SUMS, 0, 6*512*sizeof(float), stream);

    transpose_f<<<NB*32, 256, 0, stream>>>(f, FT);
    geoBC_kernel<<<ROWS, 256, 0, stream>>>(xyz, W_geo, A);
    featAC_kernel<<<ROWS, 256, 0, stream>>>(FT, W_feat, X);
    knn_kernel<<<ROWS/4, 256, 0, stream>>>(xyz, IDX);

    stats_gf<<<256, 256, 0, stream>>>(A, X, IDX, g_geo, g_feat, S_GF, CSEL);
    bn_finalize_gf<<<1, 256, 0, stream>>>(S_GF, g_geo, b_geo, g_feat, b_feat, T_GF);
    feature_maxsel<<<256, 256, 0, stream>>>(CSEL, T_GF, A, S_BN1);   // feature_ -> A  (CSEL dead)
    bn_finalize<<<1, 256, 0, stream>>>(S_BN1, g_bn, b_bn, T_BN1, 1.0f/(float)ROWS);
    affine_kernel<<<ROWS, 256, 0, stream>>>(A, T_BN1, X, 0);         // x -> X

    gemm_nt<<<dim3(ROWS/64, 4), 256, 0, stream>>>(X, W_q, QBF, 256, 256, nullptr);  // QBF over dead CSEL
    gemm_nt<<<dim3(ROWS/64, 4), 256, 0, stream>>>(X, W_k, KBF, 256, 256, nullptr);
    gemm_nt<<<dim3(ROWS/64, 4), 256, 0, stream>>>(X, W_v, VBF, 256, 256, nullptr);  // X dead after this
    colstats<<<256, 256, 0, stream>>>(QBF, S_Q);
    colstats<<<256, 256, 0, stream>>>(KBF, S_K);
    colstats<<<256, 256, 0, stream>>>(VBF, S_V);
    bn_finalize<<<1, 256, 0, stream>>>(S_Q, g_q, b_q, T_Q, 1.0f/(float)ROWS);
    bn_finalize<<<1, 256, 0, stream>>>(S_K, g_k, b_k, T_K, 1.0f/(float)ROWS);
    bn_finalize<<<1, 256, 0, stream>>>(S_V, g_v, b_v, T_V, 1.0f/(float)ROWS);
    affine_bf16_kernel<<<ROWS, 256, 0, stream>>>(QBF, T_Q, QB16);    // [19,23) over dead X
    affine_bf16_kernel<<<ROWS, 256, 0, stream>>>(KBF, T_K, KB16);    // [23,27); KBF dead after
    affine_bf16_kernel<<<ROWS, 256, 0, stream>>>(VBF, T_V, VB16);    // [27,31) over dead KBF; VBF dead after

    attn_mfma<<<dim3(NPTS/64, NHEADS, NB), 256, 0, stream>>>(QB16, KB16, VB16, OBUF);  // OBUF [31,45) over dead VBF

    gemm_nt<<<dim3(ROWS/64, 4), 256, 0, stream>>>(OBUF, W_fus, FUS, 448, 256, bias_fus); // FUS over dead QBF
    colstats<<<256, 256, 0, stream>>>(FUS, S_FUS);
    bn_finalize<<<1, 256, 0, stream>>>(S_FUS, g_fus, b_fus, T_FUS, 1.0f/(float)ROWS);
    affine_kernel<<<ROWS, 256, 0, stream>>>(FUS, T_FUS, FUS, 1);

    ln_kernel<<<ROWS, 256, 0, stream>>>(FUS, A, g_ln, b_ln, YB);     // feature__ in FUS, y -> YB (QB16/KB16 dead)
    gemm_nt<<<dim3(ROWS/64, 4), 256, 0, stream>>>(YB, W_mlp, MLP, 256, 256, bias_mlp);  // MLP over dead VB16
    out_kernel<<<dim3(NPTS/64, 4, NB), 256, 0, stream>>>(FUS, MLP, (float*)d_out);
}

// Round 7
// 556.227 us; speedup vs baseline: 2.0561x; 1.2708x over previous
//
#include <hip/hip_runtime.h>
#include <math.h>

#define NB    4
#define NPTS  2048
#define ROWS  (NB*NPTS)   // 8192
#define CIN   64
#define COUT  256
#define KNBR  21
#define NHEADS 7
#define WCH   64
#define DSH   32

typedef __attribute__((ext_vector_type(8))) short short8;
typedef __attribute__((ext_vector_type(4))) float floatx4;

__device__ __forceinline__ ushort f2bf(float x) {
    unsigned u = __float_as_uint(x);
    u += 0x7fffu + ((u >> 16) & 1u);   // RNE
    return (ushort)(u >> 16);
}
__device__ __forceinline__ float bf2f(ushort u) {
    return __uint_as_float(((unsigned)u) << 16);
}

// ---------------------------------------------------------------- geoBC (+ zero SUMS in blocks 0..11)
__global__ __launch_bounds__(256) void geoBC_kernel(const float* __restrict__ xyz, const float* __restrict__ Wg,
                                                    float* __restrict__ geoBC, float* __restrict__ sums) {
    if (blockIdx.x < 12) sums[blockIdx.x*256 + threadIdx.x] = 0.f;
    int i = blockIdx.x*256 + threadIdx.x;
    int p = i >> 8, c = i & 255, cc = c & 127;
    float x = xyz[p*3+0], y = xyz[p*3+1], z = xyz[p*3+2];
    const float* w = Wg + cc*6;
    float s;
    if (c < 128) s = (w[3]*x + w[4]*y) + w[5]*z;
    else         s = ((w[0]-w[3])*x + (w[1]-w[4])*y) + (w[2]-w[5])*z;
    geoBC[i] = s;
}

// ---------------------------------------------------------------- featAC as GEMM: X[p][c] = dot_k f[b][k][n] * Wsel[c][k]
// A staged K-major straight from f's [cin][n] layout (transpose is free).
__global__ __launch_bounds__(256) void gemm_feat(const float* __restrict__ f, const float* __restrict__ Wf,
                                                 float* __restrict__ X) {
    __shared__ float As[16][68];
    __shared__ float Ws[16][68];
    int t = threadIdx.x;
    int tx = t & 15, ty = t >> 4;
    int r0 = blockIdx.x * 64, n0 = blockIdx.y * 64;
    int b = r0 >> 11, nbase = r0 & 2047;
    float acc[4][4];
#pragma unroll
    for (int i = 0; i < 4; i++)
#pragma unroll
        for (int j = 0; j < 4; j++) acc[i][j] = 0.f;
    int m64 = t & 63, kg = t >> 6;        // A staging: coalesced along n
    int lk = t & 15, lm = t >> 4;         // W staging: coalesced along k
    for (int k0 = 0; k0 < 64; k0 += 16) {
#pragma unroll
        for (int p = 0; p < 4; p++) {
            int k = kg*4 + p;
            As[k][m64] = f[(size_t)b*CIN*NPTS + (size_t)(k0 + k)*NPTS + nbase + m64];
        }
#pragma unroll
        for (int i2 = 0; i2 < 4; i2++) {
            int cg = n0 + lm + 16*i2;
            Ws[lk][lm + 16*i2] = Wf[(size_t)(cg & 127)*128 + (cg >> 7)*64 + k0 + lk];
        }
        __syncthreads();
#pragma unroll
        for (int kq = 0; kq < 16; kq++) {
            float4 a  = *(const float4*)&As[kq][4*ty];
            float4 b4 = *(const float4*)&Ws[kq][4*tx];
            float av[4] = {a.x, a.y, a.z, a.w};
            float bv[4] = {b4.x, b4.y, b4.z, b4.w};
#pragma unroll
            for (int i = 0; i < 4; i++)
#pragma unroll
                for (int j = 0; j < 4; j++) acc[i][j] = fmaf(av[i], bv[j], acc[i][j]);
        }
        __syncthreads();
    }
#pragma unroll
    for (int i = 0; i < 4; i++)
#pragma unroll
        for (int j = 0; j < 4; j++)
            X[(size_t)(r0 + 4*ty + i)*256 + n0 + 4*tx + j] = acc[i][j];
}

// ---------------------------------------------------------------- KNN in FLOAT64 (exact ordering)
__global__ __launch_bounds__(256) void knn_kernel(const float* __restrict__ xyz, int* __restrict__ idx) {
    __shared__ float sx[NPTS*3];
    int blk = blockIdx.x;
    int b = blk >> 9;
    int g = blk & 511;
    int t = threadIdx.x;
    for (int i = t; i < NPTS*3; i += 256) sx[i] = xyz[(size_t)b*NPTS*3 + i];
    __syncthreads();
    int wave = t >> 6, lane = t & 63;
    int n = g*4 + wave;
    double qx = (double)sx[n*3], qy = (double)sx[n*3+1], qz = (double)sx[n*3+2];
    double sqn = qx*qx + qy*qy + qz*qz;
    double d[32];
#pragma unroll
    for (int i = 0; i < 32; i++) {
        int m = lane + (i << 6);
        double x = (double)sx[m*3], y = (double)sx[m*3+1], z = (double)sx[m*3+2];
        double sqm = x*x + y*y + z*z;
        double dt  = qx*x + qy*y + qz*z;
        d[i] = (sqn + sqm) - 2.0*dt;
    }
    double lv = d[0]; int li = 0;
#pragma unroll
    for (int i = 1; i < 32; i++) if (d[i] < lv) { lv = d[i]; li = i; }
    for (int kk = 0; kk < KNBR; kk++) {
        double bv = lv;
        unsigned bi = (unsigned)(lane + (li << 6));
        for (int off = 1; off < 64; off <<= 1) {
            double   ov = __shfl_xor(bv, off, 64);
            unsigned oi = __shfl_xor(bi, off, 64);
            if (ov < bv || (ov == bv && oi < bi)) { bv = ov; bi = oi; }
        }
        int m = (int)bi;
        if (lane == 0) idx[((size_t)b*NPTS + n)*KNBR + kk] = m;
        bool mine = ((m & 63) == lane);
        int slot = m >> 6;
#pragma unroll
        for (int i = 0; i < 32; i++) if (mine && slot == i) d[i] = INFINITY;
        if (mine) {
            lv = d[0]; li = 0;
#pragma unroll
            for (int i = 1; i < 32; i++) if (d[i] < lv) { lv = d[i]; li = i; }
        }
    }
}

// ---------------------------------------------------------------- stats + sign-selected extreme over K
__global__ __launch_bounds__(256) void stats_gf(const float* __restrict__ geoBC, const float* __restrict__ featAC,
                                                const int* __restrict__ idx, const float* __restrict__ g_geo,
                                                const float* __restrict__ g_feat,
                                                float* __restrict__ sums, float* __restrict__ xsel) {
    int c = threadIdx.x;
    int cc = c & 127;
    const float* base = (c < 128) ? geoBC : featAC;
    bool wantmax = ((c < 128) ? g_geo[cc] : g_feat[cc]) >= 0.f;
    float s = 0.f, ss = 0.f;
    int r0 = blockIdx.x * 32;
    for (int r = r0; r < r0 + 32; r++) {
        int b = r >> 11;
        float ctr = base[(size_t)r*256 + 128 + cc];
        float mx = -1e30f, mn = 1e30f;
        const int* ip = idx + (size_t)r*KNBR;
        for (int kk = 0; kk < KNBR; kk++) {
            int j = ip[kk];
            float xv = ctr + base[((size_t)(b*NPTS + j))*256 + cc];
            mx = fmaxf(mx, xv); mn = fminf(mn, xv);
            s += xv; ss += xv*xv;
        }
        xsel[(size_t)r*256 + c] = wantmax ? mx : mn;
    }
    atomicAdd(&sums[c], s);
    atomicAdd(&sums[256 + c], ss);
}

__global__ void bn_finalize_gf(const float* __restrict__ sums, const float* __restrict__ g_geo,
                               const float* __restrict__ b_geo, const float* __restrict__ g_feat,
                               const float* __restrict__ b_feat, float* __restrict__ st) {
    int c = threadIdx.x;
    const float inv = 1.0f / (float)(ROWS*KNBR);
    float mean = sums[c]*inv;
    float var  = sums[256+c]*inv - mean*mean;
    float g  = (c < 128) ? g_geo[c] : g_feat[c-128];
    float bb = (c < 128) ? b_geo[c] : b_feat[c-128];
    float s = g / sqrtf(var + 1e-5f);
    st[c] = s; st[256+c] = bb - mean*s;
}

__global__ void bn_finalize(const float* __restrict__ sums, const float* __restrict__ g,
                            const float* __restrict__ b, float* __restrict__ st, float inv_cnt) {
    int c = threadIdx.x;
    float mean = sums[c]*inv_cnt;
    float var  = sums[256+c]*inv_cnt - mean*mean;
    float s = g[c] / sqrtf(var + 1e-5f);
    st[c] = s; st[256+c] = b[c] - mean*s;
}

// 768-ch finalize for q/k/v: sums at SUMS+1024+g*512, out at ST+1024+g*512
__global__ void bn_finalize_qkv(const float* __restrict__ sums, const float* __restrict__ g_q,
                                const float* __restrict__ b_q, const float* __restrict__ g_k,
                                const float* __restrict__ b_k, const float* __restrict__ g_v,
                                const float* __restrict__ b_v, float* __restrict__ st) {
    int c = threadIdx.x;            // 0..767
    int g = c >> 8, cc = c & 255;
    const float* S = sums + 1024 + g*512;
    float mean = S[cc] * (1.0f/(float)ROWS);
    float var  = S[256+cc] * (1.0f/(float)ROWS) - mean*mean;
    const float* gg = (g==0) ? g_q : (g==1) ? g_k : g_v;
    const float* bb = (g==0) ? b_q : (g==1) ? b_k : b_v;
    float s = gg[cc] / sqrtf(var + 1e-5f);
    float* T = st + 1024 + g*512;
    T[cc] = s; T[256+cc] = bb[cc] - mean*s;
}

// ---------------------------------------------------------------- feature_ = relu(affine(xsel)) ; + bn1 stats
__global__ __launch_bounds__(256) void feature_maxsel(const float* __restrict__ xsel, const float* __restrict__ st,
                                                      float* __restrict__ feat, float* __restrict__ sums_bn1) {
    int c = threadIdx.x;
    float sc = st[c], tt = st[256+c];
    float s = 0.f, ss = 0.f;
    int r0 = blockIdx.x*32;
    for (int r = r0; r < r0+32; r++) {
        size_t i = (size_t)r*256 + c;
        float y = fmaxf(fmaf(sc, xsel[i], tt), 0.f);
        feat[i] = y; s += y; ss += y*y;
    }
    atomicAdd(&sums_bn1[c], s); atomicAdd(&sums_bn1[256+c], ss);
}

// ---------------------------------------------------------------- merged q/k/v GEMM: affine-x on A-load, bf16 out, stats epilogue
__global__ __launch_bounds__(256) void gemm_qkv(const float* __restrict__ A, const float* __restrict__ bnst,
                                                const float* __restrict__ Wq, const float* __restrict__ Wk,
                                                const float* __restrict__ Wv,
                                                ushort* __restrict__ QKV16, float* __restrict__ sums) {
    __shared__ float As[16][68];
    __shared__ float Ws[16][68];
    __shared__ float red[4][64][2];
    int t = threadIdx.x;
    int tx = t & 15, ty = t >> 4;
    int r0 = blockIdx.x * 64, n0 = blockIdx.y * 64;
    int wsel = n0 >> 8, nrow0 = n0 & 255;
    const float* W = (wsel == 0) ? Wq : (wsel == 1) ? Wk : Wv;
    float acc[4][4];
#pragma unroll
    for (int i = 0; i < 4; i++)
#pragma unroll
        for (int j = 0; j < 4; j++) acc[i][j] = 0.f;
    int lk = t & 15, lm = t >> 4;
    for (int k0 = 0; k0 < 256; k0 += 16) {
        float sc = bnst[k0 + lk], sh = bnst[256 + k0 + lk];
#pragma unroll
        for (int i2 = 0; i2 < 4; i2++) {
            As[lk][lm + 16*i2] = fmaf(sc, A[(size_t)(r0 + lm + 16*i2)*256 + k0 + lk], sh);
            Ws[lk][lm + 16*i2] = W[(size_t)(nrow0 + lm + 16*i2)*256 + k0 + lk];
        }
        __syncthreads();
#pragma unroll
        for (int kq = 0; kq < 16; kq++) {
            float4 a  = *(const float4*)&As[kq][4*ty];
            float4 b4 = *(const float4*)&Ws[kq][4*tx];
            float av[4] = {a.x, a.y, a.z, a.w};
            float bv[4] = {b4.x, b4.y, b4.z, b4.w};
#pragma unroll
            for (int i = 0; i < 4; i++)
#pragma unroll
                for (int j = 0; j < 4; j++) acc[i][j] = fmaf(av[i], bv[j], acc[i][j]);
        }
        __syncthreads();
    }
    // bf16 store + exact fp32 stats
    float ps[4], pss[4];
#pragma unroll
    for (int j = 0; j < 4; j++) { ps[j] = 0.f; pss[j] = 0.f; }
#pragma unroll
    for (int i = 0; i < 4; i++) {
        ushort uv[4];
#pragma unroll
        for (int j = 0; j < 4; j++) {
            float v = acc[i][j];
            ps[j] += v; pss[j] += v*v;
            uv[j] = f2bf(v);
        }
        *(uint2*)&QKV16[(size_t)(r0 + 4*ty + i)*768 + n0 + 4*tx] = *(uint2*)uv;
    }
#pragma unroll
    for (int j = 0; j < 4; j++) {
        ps[j]  += __shfl_xor(ps[j], 16, 64);  ps[j]  += __shfl_xor(ps[j], 32, 64);
        pss[j] += __shfl_xor(pss[j], 16, 64); pss[j] += __shfl_xor(pss[j], 32, 64);
    }
    int wv = t >> 6, lane = t & 63;
    if (lane < 16) {
#pragma unroll
        for (int j = 0; j < 4; j++) {
            red[wv][4*tx + j][0] = ps[j];
            red[wv][4*tx + j][1] = pss[j];
        }
    }
    __syncthreads();
    if (t < 128) {
        int col = t >> 1, which = t & 1;
        float v = red[0][col][which] + red[1][col][which] + red[2][col][which] + red[3][col][which];
        int g = n0 + col;
        atomicAdd(&sums[1024 + (g >> 8)*512 + which*256 + (g & 255)], v);
    }
}

// ---------------------------------------------------------------- affine+relu+bf16 for q/k (row-major) and v (transposed)
__global__ __launch_bounds__(256) void affine_qkv(const ushort* __restrict__ QKV16, const float* __restrict__ st,
                                                  ushort* __restrict__ qk, ushort* __restrict__ vt) {
    __shared__ ushort tile[64][72];
    int t = threadIdx.x;
    int r0 = blockIdx.x * 64, c0 = blockIdx.y * 64;
    int b = r0 >> 11, nbase = r0 & 2047;
    if (c0 < 512) {
#pragma unroll
        for (int rep = 0; rep < 16; rep++) {
            int e = t + 256*rep;
            int row = e >> 6, c = e & 63;
            int col = c0 + c, g = col >> 8, cc = col & 255;
            float v = bf2f(QKV16[(size_t)(r0 + row)*768 + col]);
            v = fmaxf(fmaf(st[1024 + g*512 + cc], v, st[1024 + g*512 + 256 + cc]), 0.f);
            qk[(size_t)(r0 + row)*512 + col] = f2bf(v);
        }
    } else {
#pragma unroll
        for (int rep = 0; rep < 16; rep++) {
            int e = t + 256*rep;
            int row = e >> 6, c = e & 63;
            int col = c0 + c, cc = col & 255;
            float v = bf2f(QKV16[(size_t)(r0 + row)*768 + col]);
            v = fmaxf(fmaf(st[1024 + 2*512 + cc], v, st[1024 + 2*512 + 256 + cc]), 0.f);
            tile[c][row] = f2bf(v);
        }
        __syncthreads();
#pragma unroll
        for (int rep = 0; rep < 16; rep++) {
            int e = t + 256*rep;
            int cc = e >> 6, nn = e & 63;
            vt[((size_t)(b*256 + (c0 - 512) + cc))*2048 + nbase + nn] = tile[cc][nn];
        }
    }
}

// ---------------------------------------------------------------- MFMA bf16 flash attention, 2 Q-tiles (128 rows)/block
// K [key][64d pad72], Vt [dim][64k pad72], P [128row][64k pad72] — padded rows: <=2-way bank aliasing (free).
__global__ __launch_bounds__(256) void attn2(const ushort* __restrict__ qk, const ushort* __restrict__ vt,
                                             float* __restrict__ obuf) {
    __shared__ ushort Ksh[64*72];
    __shared__ ushort Vts[64*72];
    __shared__ ushort Psh[128*72];
    int h = blockIdx.y, b = blockIdx.z;
    int r0 = blockIdx.x * 128;
    int t = threadIdx.x;
    int w = t >> 6, lane = t & 63;
    int r15 = lane & 15, quad = lane >> 4;
    size_t rowbase = (size_t)b*NPTS;
    int hoff = h*DSH;

    short8 aq[2][2];
#pragma unroll
    for (int u = 0; u < 2; u++)
#pragma unroll
        for (int s = 0; s < 2; s++)
            aq[u][s] = *(const short8*)(qk + (rowbase + r0 + 64*u + 16*w + r15)*512 + hoff + 32*s + 8*quad);

    floatx4 zero4 = {0.f, 0.f, 0.f, 0.f};
    floatx4 oacc[2][4];
    float mrun[2][4], lrun[2][4];
#pragma unroll
    for (int u = 0; u < 2; u++)
#pragma unroll
        for (int i = 0; i < 4; i++) { oacc[u][i] = zero4; mrun[u][i] = -1e30f; lrun[u][i] = 0.f; }

    for (int m0 = 0; m0 < NPTS; m0 += 64) {
        // stage K (key-major) and V^T (dim-major), all b128
#pragma unroll
        for (int rep = 0; rep < 2; rep++) {
            int e = t + 256*rep;
            int rr = e >> 3, c = e & 7;
            *(uint4*)&Ksh[rr*72 + 8*c] =
                *(const uint4*)(qk + (rowbase + m0 + rr)*512 + 256 + hoff + 8*c);
            *(uint4*)&Vts[rr*72 + 8*c] =
                *(const uint4*)(vt + ((size_t)(b*256 + hoff + rr))*2048 + m0 + 8*c);
        }
        __syncthreads();

        // S = Q K^T
        floatx4 sacc[2][4];
#pragma unroll
        for (int u = 0; u < 2; u++)
#pragma unroll
            for (int tt = 0; tt < 4; tt++) sacc[u][tt] = zero4;
#pragma unroll
        for (int tt = 0; tt < 4; tt++) {
            int key = 16*tt + r15;
#pragma unroll
            for (int s = 0; s < 2; s++) {
                short8 kf = *(const short8*)&Ksh[key*72 + 32*s + 8*quad];
#pragma unroll
                for (int u = 0; u < 2; u++)
                    sacc[u][tt] = __builtin_amdgcn_mfma_f32_16x16x32_bf16(aq[u][s], kf, sacc[u][tt], 0, 0, 0);
            }
        }

        // online softmax per q-tile
        float pm[2][4][4];
#pragma unroll
        for (int u = 0; u < 2; u++)
#pragma unroll
            for (int reg = 0; reg < 4; reg++) {
                float rmax = fmaxf(fmaxf(sacc[u][0][reg], sacc[u][1][reg]),
                                   fmaxf(sacc[u][2][reg], sacc[u][3][reg]));
#pragma unroll
                for (int msk = 1; msk < 16; msk <<= 1) rmax = fmaxf(rmax, __shfl_xor(rmax, msk, 64));
                float mnew = fmaxf(mrun[u][reg], rmax);
                float alpha = __expf(mrun[u][reg] - mnew);
                float rs = 0.f;
#pragma unroll
                for (int tt = 0; tt < 4; tt++) {
                    float p = __expf(sacc[u][tt][reg] - mnew);
                    pm[u][tt][reg] = p; rs += p;
                }
#pragma unroll
                for (int msk = 1; msk < 16; msk <<= 1) rs += __shfl_xor(rs, msk, 64);
                lrun[u][reg] = lrun[u][reg]*alpha + rs;
                mrun[u][reg] = mnew;
#pragma unroll
                for (int td = 0; td < 4; td++) oacc[u][td][reg] *= alpha;
            }

        // write P
#pragma unroll
        for (int u = 0; u < 2; u++)
#pragma unroll
            for (int reg = 0; reg < 4; reg++) {
                int row = 64*u + 16*w + 4*quad + reg;
#pragma unroll
                for (int tt = 0; tt < 4; tt++)
                    Psh[row*72 + 16*tt + r15] = f2bf(pm[u][tt][reg]);
            }
        __syncthreads();

        // O += P V
#pragma unroll
        for (int s = 0; s < 2; s++) {
            short8 pf[2];
#pragma unroll
            for (int u = 0; u < 2; u++)
                pf[u] = *(const short8*)&Psh[(64*u + 16*w + r15)*72 + 32*s + 8*quad];
#pragma unroll
            for (int td = 0; td < 4; td++) {
                short8 vf = *(const short8*)&Vts[(16*td + r15)*72 + 32*s + 8*quad];
#pragma unroll
                for (int u = 0; u < 2; u++)
                    oacc[u][td] = __builtin_amdgcn_mfma_f32_16x16x32_bf16(pf[u], vf, oacc[u][td], 0, 0, 0);
            }
        }
        __syncthreads();
    }

    // epilogue
#pragma unroll
    for (int u = 0; u < 2; u++)
#pragma unroll
        for (int reg = 0; reg < 4; reg++) {
            int grow = r0 + 64*u + 16*w + 4*quad + reg;
            float invl = 1.f / lrun[u][reg];
#pragma unroll
            for (int td = 0; td < 4; td++)
                obuf[(rowbase + grow)*(size_t)(NHEADS*WCH) + h*WCH + 16*td + r15] = oacc[u][td][reg]*invl;
        }
}

// ---------------------------------------------------------------- fus GEMM (bias, fp32 out, stats epilogue)
__global__ __launch_bounds__(256) void gemm_fus(const float* __restrict__ A, const float* __restrict__ W,
                                                const float* __restrict__ bias, float* __restrict__ C,
                                                float* __restrict__ sums) {
    __shared__ float As[16][68];
    __shared__ float Ws[16][68];
    __shared__ float red[4][64][2];
    int t = threadIdx.x;
    int tx = t & 15, ty = t >> 4;
    int r0 = blockIdx.x * 64, n0 = blockIdx.y * 64;
    float acc[4][4];
#pragma unroll
    for (int i = 0; i < 4; i++)
#pragma unroll
        for (int j = 0; j < 4; j++) acc[i][j] = 0.f;
    int lk = t & 15, lm = t >> 4;
    for (int k0 = 0; k0 < 448; k0 += 16) {
#pragma unroll
        for (int i2 = 0; i2 < 4; i2++) {
            As[lk][lm + 16*i2] = A[(size_t)(r0 + lm + 16*i2)*448 + k0 + lk];
            Ws[lk][lm + 16*i2] = W[(size_t)(n0 + lm + 16*i2)*448 + k0 + lk];
        }
        __syncthreads();
#pragma unroll
        for (int kq = 0; kq < 16; kq++) {
            float4 a  = *(const float4*)&As[kq][4*ty];
            float4 b4 = *(const float4*)&Ws[kq][4*tx];
            float av[4] = {a.x, a.y, a.z, a.w};
            float bv[4] = {b4.x, b4.y, b4.z, b4.w};
#pragma unroll
            for (int i = 0; i < 4; i++)
#pragma unroll
                for (int j = 0; j < 4; j++) acc[i][j] = fmaf(av[i], bv[j], acc[i][j]);
        }
        __syncthreads();
    }
    float ps[4], pss[4];
#pragma unroll
    for (int j = 0; j < 4; j++) { ps[j] = 0.f; pss[j] = 0.f; }
#pragma unroll
    for (int i = 0; i < 4; i++)
#pragma unroll
        for (int j = 0; j < 4; j++) {
            float v = acc[i][j] + bias[n0 + 4*tx + j];
            C[(size_t)(r0 + 4*ty + i)*256 + n0 + 4*tx + j] = v;
            ps[j] += v; pss[j] += v*v;
        }
#pragma unroll
    for (int j = 0; j < 4; j++) {
        ps[j]  += __shfl_xor(ps[j], 16, 64);  ps[j]  += __shfl_xor(ps[j], 32, 64);
        pss[j] += __shfl_xor(pss[j], 16, 64); pss[j] += __shfl_xor(pss[j], 32, 64);
    }
    int wv = t >> 6, lane = t & 63;
    if (lane < 16) {
#pragma unroll
        for (int j = 0; j < 4; j++) {
            red[wv][4*tx + j][0] = ps[j];
            red[wv][4*tx + j][1] = pss[j];
        }
    }
    __syncthreads();
    if (t < 128) {
        int col = t >> 1, which = t & 1;
        float v = red[0][col][which] + red[1][col][which] + red[2][col][which] + red[3][col][which];
        atomicAdd(&sums[2560 + which*256 + n0 + col], v);
    }
}

// ---------------------------------------------------------------- fused: fus-affine+relu + residual + LayerNorm
__global__ __launch_bounds__(256) void ln_fused(float* __restrict__ fusp, const float* __restrict__ feature,
                                                const float* __restrict__ st,
                                                const float* __restrict__ g_ln, const float* __restrict__ b_ln,
                                                float* __restrict__ y) {
    int r = blockIdx.x, c = threadIdx.x;
    size_t i = (size_t)r*256 + c;
    float fus = fmaxf(fmaf(st[2560 + c], fusp[i], st[2560 + 256 + c]), 0.f);
    float v = fus + feature[i];
    float s = v, ss = v*v;
    for (int m = 1; m < 64; m <<= 1) { s += __shfl_xor(s, m, 64); ss += __shfl_xor(ss, m, 64); }
    __shared__ float red[8];
    int wave = c >> 6, lane = c & 63;
    if (lane == 0) { red[wave] = s; red[4+wave] = ss; }
    __syncthreads();
    s  = red[0]+red[1]+red[2]+red[3];
    ss = red[4]+red[5]+red[6]+red[7];
    float mean = s * (1.f/256.f);
    float var  = ss * (1.f/256.f) - mean*mean;
    float rin  = 1.f/sqrtf(var + 1e-5f);
    fusp[i] = v;                                   // feature__ in place
    y[i] = (v - mean)*rin*g_ln[c] + b_ln[c];
}

// ---------------------------------------------------------------- MLP GEMM + residual + transposed store to d_out
__global__ __launch_bounds__(256) void gemm_mlp(const float* __restrict__ A, const float* __restrict__ W,
                                                const float* __restrict__ bias, const float* __restrict__ FF,
                                                float* __restrict__ outp) {
    __shared__ float As[16][68];
    __shared__ float Ws[16][68];
    __shared__ float tr[64][65];
    int t = threadIdx.x;
    int tx = t & 15, ty = t >> 4;
    int r0 = blockIdx.x * 64, n0 = blockIdx.y * 64;
    float acc[4][4];
#pragma unroll
    for (int i = 0; i < 4; i++)
#pragma unroll
        for (int j = 0; j < 4; j++) acc[i][j] = 0.f;
    int lk = t & 15, lm = t >> 4;
    for (int k0 = 0; k0 < 256; k0 += 16) {
#pragma unroll
        for (int i2 = 0; i2 < 4; i2++) {
            As[lk][lm + 16*i2] = A[(size_t)(r0 + lm + 16*i2)*256 + k0 + lk];
            Ws[lk][lm + 16*i2] = W[(size_t)(n0 + lm + 16*i2)*256 + k0 + lk];
        }
        __syncthreads();
#pragma unroll
        for (int kq = 0; kq < 16; kq++) {
            float4 a  = *(const float4*)&As[kq][4*ty];
            float4 b4 = *(const float4*)&Ws[kq][4*tx];
            float av[4] = {a.x, a.y, a.z, a.w};
            float bv[4] = {b4.x, b4.y, b4.z, b4.w};
#pragma unroll
            for (int i = 0; i < 4; i++)
#pragma unroll
                for (int j = 0; j < 4; j++) acc[i][j] = fmaf(av[i], bv[j], acc[i][j]);
        }
        __syncthreads();
    }
#pragma unroll
    for (int i = 0; i < 4; i++)
#pragma unroll
        for (int j = 0; j < 4; j++) {
            float v = acc[i][j] + bias[n0 + 4*tx + j] + FF[(size_t)(r0 + 4*ty + i)*256 + n0 + 4*tx + j];
            tr[4*tx + j][4*ty + i] = v;
        }
    __syncthreads();
    int b = r0 >> 11, nbase = r0 & 2047;
#pragma unroll
    for (int rep = 0; rep < 16; rep++) {
        int e = t + 256*rep;
        int cl = e >> 6, nl = e & 63;
        outp[((size_t)(b*256 + n0 + cl))*2048 + nbase + nl] = tr[cl][nl];
    }
}

// ================================================================ host
extern "C" void kernel_launch(void* const* d_in, const int* in_sizes, int n_in,
                              void* d_out, int out_size, void* d_ws, size_t ws_size,
                              hipStream_t stream) {
    const float* xyz    = (const float*)d_in[0];
    const float* f      = (const float*)d_in[1];
    const float* W_geo  = (const float*)d_in[2];
    const float* g_geo  = (const float*)d_in[3];
    const float* b_geo  = (const float*)d_in[4];
    const float* W_feat = (const float*)d_in[5];
    const float* g_feat = (const float*)d_in[6];
    const float* b_feat = (const float*)d_in[7];
    const float* g_bn   = (const float*)d_in[8];
    const float* b_bn   = (const float*)d_in[9];
    const float* W_q    = (const float*)d_in[10];
    const float* g_q    = (const float*)d_in[11];
    const float* b_q    = (const float*)d_in[12];
    const float* W_k    = (const float*)d_in[13];
    const float* g_k    = (const float*)d_in[14];
    const float* b_k    = (const float*)d_in[15];
    const float* W_v    = (const float*)d_in[16];
    const float* g_v    = (const float*)d_in[17];
    const float* b_v    = (const float*)d_in[18];
    const float* W_fus  = (const float*)d_in[19];
    const float* bias_fus = (const float*)d_in[20];
    const float* g_fus  = (const float*)d_in[21];
    const float* b_fus  = (const float*)d_in[22];
    const float* g_ln   = (const float*)d_in[23];
    const float* b_ln   = (const float*)d_in[24];
    const float* W_mlp  = (const float*)d_in[25];
    const float* bias_mlp = (const float*)d_in[26];

    float* ws = (float*)d_ws;
    const size_t MBF = 262144;  // floats per MiB
    // Liveness (peak 43 MiB):
    //  [0,1)    SUMS(3072f) / ST(3072f @+4096) / IDX(@+16384f, 672KB)
    //  [1,9)    A: geoBC -> feature_ (live until ln_fused)
    //  [9,17)   X: feat (dead after stats_gf) -> QK16 bf16 (dead after attn) -> YB (y)
    //  [17,25)  CSEL (dead after maxsel) -> FUSP fp32 -> feature__ in place
    //  [25,37)  QKV16 bf16 [8192x768] (dead after affine_qkv)
    //  [25,39)  OBUF fp32 [8192x448] (written at attn, after QKV16 dead)
    //  [39,43)  VT16 bf16 [4][256][2048] (dead after attn)
    float* SUMS  = ws;
    float* ST    = ws + 4096;
    int*   IDX   = (int*)(ws + 16384);
    float* A     = ws + 1*MBF;
    float* X     = ws + 9*MBF;
    ushort* QK16 = (ushort*)(ws + 9*MBF);
    float* YB    = ws + 9*MBF;
    float* CSEL  = ws + 17*MBF;
    float* FUSP  = ws + 17*MBF;
    ushort* QKV16= (ushort*)(ws + 25*MBF);
    float* OBUF  = ws + 25*MBF;
    ushort* VT16 = (ushort*)(ws + 39*MBF);

    float* S_GF  = SUMS;        float* T_GF  = ST;
    float* S_BN1 = SUMS + 512;  float* T_BN1 = ST + 512;

    geoBC_kernel<<<ROWS, 256, 0, stream>>>(xyz, W_geo, A, SUMS);
    gemm_feat<<<dim3(128, 4), 256, 0, stream>>>(f, W_feat, X);
    knn_kernel<<<ROWS/4, 256, 0, stream>>>(xyz, IDX);

    stats_gf<<<256, 256, 0, stream>>>(A, X, IDX, g_geo, g_feat, S_GF, CSEL);
    bn_finalize_gf<<<1, 256, 0, stream>>>(S_GF, g_geo, b_geo, g_feat, b_feat, T_GF);
    feature_maxsel<<<256, 256, 0, stream>>>(CSEL, T_GF, A, S_BN1);   // feature_ -> A
    bn_finalize<<<1, 256, 0, stream>>>(S_BN1, g_bn, b_bn, T_BN1, 1.0f/(float)ROWS);

    gemm_qkv<<<dim3(128, 12), 256, 0, stream>>>(A, T_BN1, W_q, W_k, W_v, QKV16, SUMS);
    bn_finalize_qkv<<<1, 768, 0, stream>>>(SUMS, g_q, b_q, g_k, b_k, g_v, b_v, ST);
    affine_qkv<<<dim3(128, 12), 256, 0, stream>>>(QKV16, ST, QK16, VT16);

    attn2<<<dim3(NPTS/128, NHEADS, NB), 256, 0, stream>>>(QK16, VT16, OBUF);

    gemm_fus<<<dim3(128, 4), 256, 0, stream>>>(OBUF, W_fus, bias_fus, FUSP, SUMS);
    bn_finalize<<<1, 256, 0, stream>>>(SUMS + 2560, g_fus, b_fus, ST + 2560, 1.0f/(float)ROWS);
    ln_fused<<<ROWS, 256, 0, stream>>>(FUSP, A, ST, g_ln, b_ln, YB);
    gemm_mlp<<<dim3(128, 4), 256, 0, stream>>>(YB, W_mlp, bias_mlp, FUSP, (float*)d_out);
}